// Round 7
// baseline (36.489 us; speedup 1.0000x reference)
//
#include <hip/hip_runtime.h>
#include <math.h>

#define NB   64
#define D    256
#define HW   25
#define TRI  32896         // 256*257/2
#define BTS  32            // band/tile size
#define NT   36            // triu tiles per batch (8 bands)
#define PST  36            // padded p-row stride (float4-aligned, conflict-free)

// tile id t (0..35) -> band pair (bi<=bj) of 8 bands of 32 rows
__device__ __forceinline__ void tile_bands8(int t, int& bi, int& bj) {
    int acc = 0;
#pragma unroll
    for (int w = 0; w < 8; ++w) {
        const int cnt = 8 - w;
        if (t < acc + cnt) { bi = w; bj = w + (t - acc); return; }
        acc += cnt;
    }
    bi = 7; bj = 7;
}

// ---------------------------------------------------------------------------
// K1: one 32x32 triu tile per block; 64*36 = 2304 blocks = exactly 9/CU.
// 64 threads = 8(tx) x 8(ty), each a 4x4 sub-tile of
//   e(i,j) = sum_p |f_i+f_j| - |f_i-f_j|   (p-loop: 2 ds_read_b128 -> 64 VALU)
// Raw e -> d_out triu; partial row-sum vectors -> collision-free d_ws slots:
//   i-contrib of (bi,bj) -> band bi, slot bj-bi        (slots 0..7-bi)
//   j-contrib (bi<bj)    -> band bj, slot 8-bj+bi      (slots 8-bj..7)
// Every (b,band) gets slots 0..7 written exactly once.
// ---------------------------------------------------------------------------
__global__ __launch_bounds__(64) void tile_kernel(const float* __restrict__ feat,
                                                  float* __restrict__ rsp,
                                                  float* __restrict__ out) {
    __shared__ __align__(16) float as[HW * PST];
    __shared__ __align__(16) float bs[HW * PST];
    __shared__ float red0[BTS][9];   // i-partials, reduce over tx (8)
    __shared__ float red1[BTS][9];   // j-partials, reduce over ty (8)

    const int tid = threadIdx.x;
    const int blk = blockIdx.x;
    const int b   = blk / NT;
    const int t   = blk - b * NT;
    int bi, bj; tile_bands8(t, bi, bj);
    const int ibase = bi * BTS, jbase = bj * BTS;
    const bool diag = (bi == bj);

    const float* fb = feat + (size_t)b * D * HW;

    // stage transposed panels; global reads coalesced (r-major contiguous 3200B)
    for (int idx = tid; idx < BTS * HW; idx += 64) {
        const int r = idx / HW, p = idx - r * HW;
        as[p * PST + r] = fb[(ibase + r) * HW + p];
    }
    if (!diag) {
        for (int idx = tid; idx < BTS * HW; idx += 64) {
            const int r = idx / HW, p = idx - r * HW;
            bs[p * PST + r] = fb[(jbase + r) * HW + p];
        }
    }
    __syncthreads();

    const float* bsp = diag ? as : bs;
    const int tx = tid & 7;
    const int ty = tid >> 3;

    float acc[4][4] = {{0.f}};
#pragma unroll
    for (int p = 0; p < HW; ++p) {
        float4 av = *reinterpret_cast<const float4*>(&as[p * PST + ty * 4]);
        float4 bv = *reinterpret_cast<const float4*>(&bsp[p * PST + tx * 4]);
        float a4[4] = {av.x, av.y, av.z, av.w};
        float b4[4] = {bv.x, bv.y, bv.z, bv.w};
#pragma unroll
        for (int r = 0; r < 4; ++r)
#pragma unroll
            for (int q = 0; q < 4; ++q)
                acc[r][q] += fabsf(a4[r] + b4[q]) - fabsf(a4[r] - b4[q]);
    }

    // raw e -> d_out triu (diag masks j>=i; e itself is symmetric so the full
    // 4x4 still feeds the i-partials correctly)
    float* ob = out + (size_t)b * TRI;
    if (diag) {
#pragma unroll
        for (int r = 0; r < 4; ++r) {
            const int i = ibase + ty * 4 + r;
            const int rowoff = (i * (513 - i)) >> 1;
#pragma unroll
            for (int q = 0; q < 4; ++q) {
                const int j = jbase + tx * 4 + q;
                if (j >= i) ob[rowoff + (j - i)] = acc[r][q];
            }
        }
    } else {
#pragma unroll
        for (int r = 0; r < 4; ++r) {
            const int i = ibase + ty * 4 + r;
            const int rowoff = (i * (513 - i)) >> 1;
#pragma unroll
            for (int q = 0; q < 4; ++q) {
                const int j = jbase + tx * 4 + q;
                ob[rowoff + (j - i)] = acc[r][q];
            }
        }
    }

    // partial row vectors
    float pi[4];
#pragma unroll
    for (int r = 0; r < 4; ++r) pi[r] = acc[r][0] + acc[r][1] + acc[r][2] + acc[r][3];
#pragma unroll
    for (int r = 0; r < 4; ++r) red0[ty * 4 + r][tx] = pi[r];
    if (!diag) {
        float pj[4];
#pragma unroll
        for (int q = 0; q < 4; ++q) pj[q] = acc[0][q] + acc[1][q] + acc[2][q] + acc[3][q];
#pragma unroll
        for (int q = 0; q < 4; ++q) red1[tx * 4 + q][ty] = pj[q];
    }
    __syncthreads();

    if (tid < BTS) {
        float s = 0.f;
#pragma unroll
        for (int x = 0; x < 8; ++x) s += red0[tid][x];
        rsp[((b * 8 + bi) * 8 + (bj - bi)) * BTS + tid] = s;
    } else if (!diag) {
        const int c = tid - BTS;
        float s = 0.f;
#pragma unroll
        for (int x = 0; x < 8; ++x) s += red1[c][x];
        rsp[((b * 8 + bj) * 8 + (8 - bj + bi)) * BTS + c] = s;
    }
}

// ---------------------------------------------------------------------------
// K2: same grid/block->tile map (L2-local RMW). Row sums = sum of the band's
// 8 slots (uniform), then in place: out = sc*(e - (rs_i+rs_j)/256).
// ---------------------------------------------------------------------------
__global__ __launch_bounds__(64) void center_kernel(const float* __restrict__ temp,
                                                    const float* __restrict__ rsp,
                                                    float* __restrict__ out) {
    __shared__ float rsum0[BTS];
    __shared__ float rsum1[BTS];

    const int tid = threadIdx.x;
    const int blk = blockIdx.x;
    const int b   = blk / NT;
    const int t   = blk - b * NT;
    int bi, bj; tile_bands8(t, bi, bj);
    const int ibase = bi * BTS, jbase = bj * BTS;
    const bool diag = (bi == bj);

    if (tid < BTS) {
        float s = 0.f;
#pragma unroll
        for (int sl = 0; sl < 8; ++sl) s += rsp[((b * 8 + bi) * 8 + sl) * BTS + tid];
        rsum0[tid] = s;
    } else {
        const int c = tid - BTS;
        float s = 0.f;
#pragma unroll
        for (int sl = 0; sl < 8; ++sl) s += rsp[((b * 8 + bj) * 8 + sl) * BTS + c];
        rsum1[c] = s;
    }
    __syncthreads();

    const int tx = tid & 7;
    const int ty = tid >> 3;
    const float sc = 0.5f * expf(temp[0]);
    float* ob = out + (size_t)b * TRI;

#pragma unroll
    for (int r = 0; r < 4; ++r) {
        const int i = ibase + ty * 4 + r;
        const int rowoff = (i * (513 - i)) >> 1;
        const float ri = rsum0[ty * 4 + r];
#pragma unroll
        for (int q = 0; q < 4; ++q) {
            const int j = jbase + tx * 4 + q;
            if (!diag || j >= i) {
                float* p = &ob[rowoff + (j - i)];
                const float e = *p;
                *p = sc * (e - (ri + rsum1[tx * 4 + q]) * (1.0f / 256.0f));
            }
        }
    }
}

extern "C" void kernel_launch(void* const* d_in, const int* in_sizes, int n_in,
                              void* d_out, int out_size, void* d_ws, size_t ws_size,
                              hipStream_t stream) {
    const float* feat = (const float*)d_in[0];
    const float* temp = (const float*)d_in[1];
    float* out = (float*)d_out;
    float* rsp = (float*)d_ws;          // 64*8*8*32 floats = 512 KB slots

    tile_kernel<<<NB * NT, 64, 0, stream>>>(feat, rsp, out);
    center_kernel<<<NB * NT, 64, 0, stream>>>(temp, rsp, out);
}